// Round 3
// baseline (34596.164 us; speedup 1.0000x reference)
//
#include <hip/hip_runtime.h>
#include <hip/hip_cooperative_groups.h>
#include <cstdint>
#include <cstddef>

namespace cg = cooperative_groups;

typedef __attribute__((ext_vector_type(8))) short short8;
typedef __attribute__((ext_vector_type(4))) short short4v;
typedef __attribute__((ext_vector_type(4))) float float4v;

#define T_STEPS 512
#define BATCH   64
#define IN_DIM  512
#define HID     1024
#define BH      (BATCH * HID)              /* 65536 */
#define OPS_SZ  ((size_t)T_STEPS * BH)     /* 33554432 */
#define NX      ((size_t)T_STEPS * BATCH * IN_DIM) /* 16777216 */

__device__ __forceinline__ float bf2f(short b) {
    return __builtin_bit_cast(float, ((unsigned)(unsigned short)b) << 16);
}
__device__ __forceinline__ short f2bf(float f) {
    unsigned u = __builtin_bit_cast(unsigned, f);
    unsigned r = (u + 0x7FFFu + ((u >> 16) & 1u)) >> 16;   // round-nearest-even
    return (short)(unsigned short)r;
}
__device__ __forceinline__ float sigmoidf_(float v) { return 1.0f / (1.0f + __expf(-v)); }

// C[64 x 16] += A[64 x Kseg] * W[16 x Kseg]^T  (this wave's K-slice).
// A: bf16-bits (short), row stride lda. W: LDS bf16-bits, row stride ldw.
template <int NC>
__device__ __forceinline__ void gemm_seg(const short* __restrict__ A, int lda,
                                         const short* __restrict__ W, int ldw,
                                         int kbase, int col, int kq, float4v* acc)
{
#pragma unroll
    for (int kc = 0; kc < NC; ++kc) {
        const int k = kbase + kc * 32 + kq * 8;
        const short8 b = *(const short8*)(W + col * ldw + k);
#pragma unroll
        for (int mt = 0; mt < 4; ++mt) {
            const short8 a = *(const short8*)(A + (size_t)(mt * 16 + col) * lda + k);
            acc[mt] = __builtin_amdgcn_mfma_f32_16x16x32_bf16(a, b, acc[mt], 0, 0, 0);
        }
    }
}

// Same, but A is fp32 in global; fragments packed to bf16 in-register.
template <int NC>
__device__ __forceinline__ void gemm_seg_f32(const float* __restrict__ A, int lda,
                                             const short* __restrict__ W, int ldw,
                                             int kbase, int col, int kq, float4v* acc)
{
#pragma unroll
    for (int kc = 0; kc < NC; ++kc) {
        const int k = kbase + kc * 32 + kq * 8;
        const short8 b = *(const short8*)(W + col * ldw + k);
#pragma unroll
        for (int mt = 0; mt < 4; ++mt) {
            const float* ap = A + (size_t)(mt * 16 + col) * lda + k;
            const float4v a0 = *(const float4v*)ap;
            const float4v a1 = *(const float4v*)(ap + 4);
            short8 a;
            a[0] = f2bf(a0[0]); a[1] = f2bf(a0[1]); a[2] = f2bf(a0[2]); a[3] = f2bf(a0[3]);
            a[4] = f2bf(a1[0]); a[5] = f2bf(a1[1]); a[6] = f2bf(a1[2]); a[7] = f2bf(a1[3]);
            acc[mt] = __builtin_amdgcn_mfma_f32_16x16x32_bf16(a, b, acc[mt], 0, 0, 0);
        }
    }
}

__global__ void __launch_bounds__(256, 1)
lstm_persistent(const float* __restrict__ xf,     // [T][B][IN] fp32
                const float* __restrict__ Wi0, const float* __restrict__ Wh0,
                const float* __restrict__ bi0, const float* __restrict__ bh0,
                const float* __restrict__ Wi1, const float* __restrict__ Wh1,
                const float* __restrict__ bi1, const float* __restrict__ bh1,
                const float* __restrict__ h0in,   // [2][B][H] fp32
                const float* __restrict__ c0in,   // [2][B][H] fp32
                float* __restrict__ out,          // fp32: ops[T,B,H], hT[2,B,H], cT[2,B,H]
                short* __restrict__ h0b,          // ws: [2][BH] bf16 layer-0 h dbuf
                short* __restrict__ h1b,          // ws: [2][BH] bf16 layer-1 h dbuf
                short* __restrict__ xbf,          // ws: [NX] bf16 x (if use_pre)
                int use_pre)
{
    // Weight rows padded +8 bf16 (16 B).
    __shared__ short w0x[16][520];    // Wi0 slice (16 x 512)
    __shared__ short w0h[16][1032];   // Wh0 slice (16 x 1024)
    __shared__ short w1x[16][1032];   // Wi1 slice
    __shared__ short w1h[16][1032];   // Wh1 slice
    __shared__ float gbuf[4][64][17]; // per-wave K-split partial gates
    __shared__ float bias0[16], bias1[16];
    __shared__ float cl0[64][4], cl1[64][4];  // fp32 cell state (WG-private slice)

    const int wg   = blockIdx.x;    // owns hidden units [4wg, 4wg+4)
    const int tid  = threadIdx.x;
    const int wave = tid >> 6;      // 0..3 = K-split
    const int lane = tid & 63;
    const int col  = lane & 15;
    const int kq   = lane >> 4;
    const int u0   = wg << 2;
    const int b    = tid >> 2;      // elementwise: batch row
    const int uu   = tid & 3;       // elementwise: unit within WG slice
    const int ug   = u0 + uu;
    const size_t ci = (size_t)b * HID + ug;

#define GROW(cc) ((size_t)((cc) >> 2) * HID + u0 + ((cc) & 3))
    // ---- stage weights into LDS (fp32 -> bf16, once) ----
    for (int idx = tid; idx < 16 * 128; idx += 256) {
        const int cc = idx >> 7, ch = (idx & 127) << 2;
        const float4v v = *(const float4v*)(Wi0 + GROW(cc) * IN_DIM + ch);
        short4v s; s[0] = f2bf(v[0]); s[1] = f2bf(v[1]); s[2] = f2bf(v[2]); s[3] = f2bf(v[3]);
        *(short4v*)&w0x[cc][ch] = s;
    }
    for (int idx = tid; idx < 16 * 256; idx += 256) {
        const int cc = idx >> 8, ch = (idx & 255) << 2;
        const size_t off = GROW(cc) * HID + ch;
        {
            const float4v v = *(const float4v*)(Wh0 + off);
            short4v s; s[0] = f2bf(v[0]); s[1] = f2bf(v[1]); s[2] = f2bf(v[2]); s[3] = f2bf(v[3]);
            *(short4v*)&w0h[cc][ch] = s;
        }
        {
            const float4v v = *(const float4v*)(Wi1 + off);
            short4v s; s[0] = f2bf(v[0]); s[1] = f2bf(v[1]); s[2] = f2bf(v[2]); s[3] = f2bf(v[3]);
            *(short4v*)&w1x[cc][ch] = s;
        }
        {
            const float4v v = *(const float4v*)(Wh1 + off);
            short4v s; s[0] = f2bf(v[0]); s[1] = f2bf(v[1]); s[2] = f2bf(v[2]); s[3] = f2bf(v[3]);
            *(short4v*)&w1h[cc][ch] = s;
        }
    }
    if (tid < 16) {
        bias0[tid] = bi0[GROW(tid)] + bh0[GROW(tid)];
        bias1[tid] = bi1[GROW(tid)] + bh1[GROW(tid)];
    }
    // ---- state init: own (b,uu) slot; h(-1) into buffer 1 ----
    cl0[b][uu] = c0in[ci];
    cl1[b][uu] = c0in[BH + ci];
    h0b[BH + ci] = f2bf(h0in[ci]);
    h1b[BH + ci] = f2bf(h0in[BH + ci]);

    // ---- pre-convert x to bf16 in ws (grid-strided) ----
    if (use_pre) {
        const size_t gtid = (size_t)blockIdx.x * 256 + tid;
        for (size_t i = gtid * 4; i < NX; i += (size_t)65536 * 4) {
            const float4v v = *(const float4v*)(xf + i);
            short4v s; s[0] = f2bf(v[0]); s[1] = f2bf(v[1]); s[2] = f2bf(v[2]); s[3] = f2bf(v[3]);
            *(short4v*)(xbf + i) = s;
        }
    }

    cg::grid_group grid = cg::this_grid();
    __threadfence();
    grid.sync();   // h inits + x conversion visible everywhere

    const float4v z = {0.f, 0.f, 0.f, 0.f};

    // Super-step s: layer 0 computes t=s, layer 1 computes t=s-1.
    for (int s = 0; s <= T_STEPS; ++s) {
        if (s > 0) { __threadfence(); grid.sync(); }

        if (s < T_STEPS) {  // ---- layer 0, t = s ----
            float4v acc[4] = {z, z, z, z};
            if (use_pre)
                gemm_seg<4>(xbf + (size_t)s * BATCH * IN_DIM, IN_DIM,
                            &w0x[0][0], 520, wave * 128, col, kq, acc);
            else
                gemm_seg_f32<4>(xf + (size_t)s * BATCH * IN_DIM, IN_DIM,
                                &w0x[0][0], 520, wave * 128, col, kq, acc);
            gemm_seg<8>(h0b + (size_t)((s + 1) & 1) * BH, HID,
                        &w0h[0][0], 1032, wave * 256, col, kq, acc);
#pragma unroll
            for (int mt = 0; mt < 4; ++mt)
#pragma unroll
                for (int r = 0; r < 4; ++r)
                    gbuf[wave][mt * 16 + kq * 4 + r][col] = acc[mt][r];
            __syncthreads();
            {
                const float gi = gbuf[0][b][uu]      + gbuf[1][b][uu]      + gbuf[2][b][uu]      + gbuf[3][b][uu]      + bias0[uu];
                const float gf = gbuf[0][b][4 + uu]  + gbuf[1][b][4 + uu]  + gbuf[2][b][4 + uu]  + gbuf[3][b][4 + uu]  + bias0[4 + uu];
                const float gg = gbuf[0][b][8 + uu]  + gbuf[1][b][8 + uu]  + gbuf[2][b][8 + uu]  + gbuf[3][b][8 + uu]  + bias0[8 + uu];
                const float go = gbuf[0][b][12 + uu] + gbuf[1][b][12 + uu] + gbuf[2][b][12 + uu] + gbuf[3][b][12 + uu] + bias0[12 + uu];
                const float cn = sigmoidf_(gf) * cl0[b][uu] + sigmoidf_(gi) * tanhf(gg);
                const float hn = sigmoidf_(go) * tanhf(cn);
                cl0[b][uu] = cn;
                h0b[(size_t)(s & 1) * BH + ci] = f2bf(hn);
            }
            __syncthreads();  // gbuf reused by layer 1
        }

        if (s >= 1) {  // ---- layer 1, t = s-1 ----
            const int t = s - 1;
            float4v acc[4] = {z, z, z, z};
            gemm_seg<8>(h0b + (size_t)(t & 1) * BH, HID,
                        &w1x[0][0], 1032, wave * 256, col, kq, acc);
            gemm_seg<8>(h1b + (size_t)(s & 1) * BH, HID,
                        &w1h[0][0], 1032, wave * 256, col, kq, acc);
#pragma unroll
            for (int mt = 0; mt < 4; ++mt)
#pragma unroll
                for (int r = 0; r < 4; ++r)
                    gbuf[wave][mt * 16 + kq * 4 + r][col] = acc[mt][r];
            __syncthreads();
            {
                const float gi = gbuf[0][b][uu]      + gbuf[1][b][uu]      + gbuf[2][b][uu]      + gbuf[3][b][uu]      + bias1[uu];
                const float gf = gbuf[0][b][4 + uu]  + gbuf[1][b][4 + uu]  + gbuf[2][b][4 + uu]  + gbuf[3][b][4 + uu]  + bias1[4 + uu];
                const float gg = gbuf[0][b][8 + uu]  + gbuf[1][b][8 + uu]  + gbuf[2][b][8 + uu]  + gbuf[3][b][8 + uu]  + bias1[8 + uu];
                const float go = gbuf[0][b][12 + uu] + gbuf[1][b][12 + uu] + gbuf[2][b][12 + uu] + gbuf[3][b][12 + uu] + bias1[12 + uu];
                const float cn = sigmoidf_(gf) * cl1[b][uu] + sigmoidf_(gi) * tanhf(gg);
                const float hn = sigmoidf_(go) * tanhf(cn);
                cl1[b][uu] = cn;
                h1b[(size_t)(t & 1) * BH + ci] = f2bf(hn);
                out[(size_t)t * BH + ci] = hn;    // ops[t] (fp32)
            }
            __syncthreads();
        }
    }

    // ---- final hT, cT (own-thread data) ----
    out[OPS_SZ + ci]                   = bf2f(h0b[(size_t)((T_STEPS - 1) & 1) * BH + ci]);
    out[OPS_SZ + BH + ci]              = bf2f(h1b[(size_t)((T_STEPS - 1) & 1) * BH + ci]);
    out[OPS_SZ + 2 * (size_t)BH + ci]  = cl0[b][uu];
    out[OPS_SZ + 3 * (size_t)BH + ci]  = cl1[b][uu];
#undef GROW
}

extern "C" void kernel_launch(void* const* d_in, const int* in_sizes, int n_in,
                              void* d_out, int out_size, void* d_ws, size_t ws_size,
                              hipStream_t stream)
{
    const float* x    = (const float*)d_in[0];
    const float* h0   = (const float*)d_in[1];
    const float* c0   = (const float*)d_in[2];
    const float* Wi0  = (const float*)d_in[3];
    const float* Wh0  = (const float*)d_in[4];
    const float* bi0  = (const float*)d_in[5];
    const float* bh0  = (const float*)d_in[6];
    const float* Wi1  = (const float*)d_in[7];
    const float* Wh1  = (const float*)d_in[8];
    const float* bi1  = (const float*)d_in[9];
    const float* bh1  = (const float*)d_in[10];
    float* out = (float*)d_out;

    // ws: [2*BH short h0 dbuf][2*BH short h1 dbuf][NX short x_bf16]
    short* h0b = (short*)d_ws;
    short* h1b = h0b + (size_t)2 * BH;
    short* xbf = h1b + (size_t)2 * BH;
    int use_pre = (ws_size >= ((size_t)4 * BH + NX) * sizeof(short)) ? 1 : 0;

    void* args[] = {(void*)&x, (void*)&Wi0, (void*)&Wh0, (void*)&bi0, (void*)&bh0,
                    (void*)&Wi1, (void*)&Wh1, (void*)&bi1, (void*)&bh1,
                    (void*)&h0, (void*)&c0, (void*)&out,
                    (void*)&h0b, (void*)&h1b, (void*)&xbf, (void*)&use_pre};
    hipLaunchCooperativeKernel((void*)lstm_persistent, dim3(256), dim3(256),
                               args, 0, stream);
}

// Round 4
// 11934.319 us; speedup vs baseline: 2.8989x; 2.8989x over previous
//
#include <hip/hip_runtime.h>
#include <hip/hip_cooperative_groups.h>
#include <cstdint>
#include <cstddef>

namespace cg = cooperative_groups;

typedef __attribute__((ext_vector_type(8))) short short8;
typedef __attribute__((ext_vector_type(4))) short short4v;
typedef __attribute__((ext_vector_type(4))) float float4v;

#define T_STEPS 512
#define BATCH   64
#define IN_DIM  512
#define HID     1024
#define BH      (BATCH * HID)              /* 65536 */
#define OPS_SZ  ((size_t)T_STEPS * BH)     /* 33554432 */
#define NX      ((size_t)T_STEPS * BATCH * IN_DIM) /* 16777216 */
#define NWG     256
#define BAR_BYTES 2048                     /* barrier state at front of ws */

__device__ __forceinline__ float bf2f(short b) {
    return __builtin_bit_cast(float, ((unsigned)(unsigned short)b) << 16);
}
__device__ __forceinline__ short f2bf(float f) {
    unsigned u = __builtin_bit_cast(unsigned, f);
    unsigned r = (u + 0x7FFFu + ((u >> 16) & 1u)) >> 16;   // round-nearest-even
    return (short)(unsigned short)r;
}
__device__ __forceinline__ float sigmoidf_(float v) { return 1.0f / (1.0f + __expf(-v)); }

// Fast grid barrier. Called by tid==0 only, inside __syncthreads brackets.
// Release: flush this XCD's L2 (h stores) to the device coherence point.
// Acquire: invalidate stale L1/L2 so post-barrier reads refill fresh.
__device__ __forceinline__ void grid_bar(unsigned* bar, int wg, unsigned e)
{
    asm volatile("s_waitcnt vmcnt(0)" ::: "memory");
    asm volatile("buffer_wbl2 sc1" ::: "memory");
    asm volatile("s_waitcnt vmcnt(0)" ::: "memory");
    unsigned* sub  = bar + (wg >> 5) * 32;   // 8 counters, 128 B apart
    unsigned* root = bar + 256;
    unsigned* go   = bar + 288;
    const unsigned old = __hip_atomic_fetch_add(sub, 1u, __ATOMIC_RELAXED, __HIP_MEMORY_SCOPE_AGENT);
    if (old == e * 32u - 1u) {               // last of this 32-WG group
        const unsigned r = __hip_atomic_fetch_add(root, 1u, __ATOMIC_RELAXED, __HIP_MEMORY_SCOPE_AGENT);
        if (r == e * 8u - 1u)                // last group
            __hip_atomic_store(go, e, __ATOMIC_RELAXED, __HIP_MEMORY_SCOPE_AGENT);
    }
    while (__hip_atomic_load(go, __ATOMIC_RELAXED, __HIP_MEMORY_SCOPE_AGENT) < e)
        __builtin_amdgcn_s_sleep(1);
    asm volatile("buffer_inv sc0 sc1" ::: "memory");
    asm volatile("s_waitcnt vmcnt(0)" ::: "memory");
}

// C[64 x 16] += A[64 x Kseg] * W[16 x Kseg]^T  (this wave's K-slice).
template <int NC>
__device__ __forceinline__ void gemm_seg(const short* __restrict__ A, int lda,
                                         const short* __restrict__ W, int ldw,
                                         int kbase, int col, int kq, float4v* acc)
{
#pragma unroll
    for (int kc = 0; kc < NC; ++kc) {
        const int k = kbase + kc * 32 + kq * 8;
        const short8 b = *(const short8*)(W + col * ldw + k);
#pragma unroll
        for (int mt = 0; mt < 4; ++mt) {
            const short8 a = *(const short8*)(A + (size_t)(mt * 16 + col) * lda + k);
            acc[mt] = __builtin_amdgcn_mfma_f32_16x16x32_bf16(a, b, acc[mt], 0, 0, 0);
        }
    }
}

// Same, but A fp32 in global; fragments packed to bf16 in-register (fallback).
template <int NC>
__device__ __forceinline__ void gemm_seg_f32(const float* __restrict__ A, int lda,
                                             const short* __restrict__ W, int ldw,
                                             int kbase, int col, int kq, float4v* acc)
{
#pragma unroll
    for (int kc = 0; kc < NC; ++kc) {
        const int k = kbase + kc * 32 + kq * 8;
        const short8 b = *(const short8*)(W + col * ldw + k);
#pragma unroll
        for (int mt = 0; mt < 4; ++mt) {
            const float* ap = A + (size_t)(mt * 16 + col) * lda + k;
            const float4v a0 = *(const float4v*)ap;
            const float4v a1 = *(const float4v*)(ap + 4);
            short8 a;
            a[0] = f2bf(a0[0]); a[1] = f2bf(a0[1]); a[2] = f2bf(a0[2]); a[3] = f2bf(a0[3]);
            a[4] = f2bf(a1[0]); a[5] = f2bf(a1[1]); a[6] = f2bf(a1[2]); a[7] = f2bf(a1[3]);
            acc[mt] = __builtin_amdgcn_mfma_f32_16x16x32_bf16(a, b, acc[mt], 0, 0, 0);
        }
    }
}

__global__ void __launch_bounds__(256, 1)
lstm_persistent(const float* __restrict__ xf,     // [T][B][IN] fp32
                const float* __restrict__ Wi0, const float* __restrict__ Wh0,
                const float* __restrict__ bi0, const float* __restrict__ bh0,
                const float* __restrict__ Wi1, const float* __restrict__ Wh1,
                const float* __restrict__ bi1, const float* __restrict__ bh1,
                const float* __restrict__ h0in,   // [2][B][H] fp32
                const float* __restrict__ c0in,   // [2][B][H] fp32
                float* __restrict__ out,          // fp32: ops[T,B,H], hT[2,B,H], cT[2,B,H]
                unsigned* __restrict__ bar,       // ws: barrier state
                short* __restrict__ h0b,          // ws: [2][BH] bf16 layer-0 h dbuf
                short* __restrict__ h1b,          // ws: [2][BH] bf16 layer-1 h dbuf
                short* __restrict__ xbf,          // ws: [NX] bf16 x (if use_pre)
                int use_pre)
{
    __shared__ short w0x[16][520];    // Wi0 slice (16 x 512), rows padded +8
    __shared__ short w0h[16][1032];   // Wh0 slice (16 x 1024)
    __shared__ short w1x[16][1032];   // Wi1 slice
    __shared__ short w1h[16][1032];   // Wh1 slice
    __shared__ float gbuf[4][64][17]; // per-wave K-split partial gates
    __shared__ float bias0[16], bias1[16];
    __shared__ float cl0[64][4], cl1[64][4];  // fp32 cell state (WG-private slice)

    const int wg   = blockIdx.x;    // owns hidden units [4wg, 4wg+4)
    const int tid  = threadIdx.x;
    const int wave = tid >> 6;      // 0..3 = K-split
    const int lane = tid & 63;
    const int col  = lane & 15;
    const int kq   = lane >> 4;
    const int u0   = wg << 2;
    const int b    = tid >> 2;      // elementwise: batch row
    const int uu   = tid & 3;       // elementwise: unit within WG slice
    const int ug   = u0 + uu;
    const size_t ci = (size_t)b * HID + ug;

#define GROW(cc) ((size_t)((cc) >> 2) * HID + u0 + ((cc) & 3))
    // ---- stage weights into LDS (fp32 -> bf16, once) ----
    for (int idx = tid; idx < 16 * 128; idx += 256) {
        const int cc = idx >> 7, ch = (idx & 127) << 2;
        const float4v v = *(const float4v*)(Wi0 + GROW(cc) * IN_DIM + ch);
        short4v s; s[0] = f2bf(v[0]); s[1] = f2bf(v[1]); s[2] = f2bf(v[2]); s[3] = f2bf(v[3]);
        *(short4v*)&w0x[cc][ch] = s;
    }
    for (int idx = tid; idx < 16 * 256; idx += 256) {
        const int cc = idx >> 8, ch = (idx & 255) << 2;
        const size_t off = GROW(cc) * HID + ch;
        {
            const float4v v = *(const float4v*)(Wh0 + off);
            short4v s; s[0] = f2bf(v[0]); s[1] = f2bf(v[1]); s[2] = f2bf(v[2]); s[3] = f2bf(v[3]);
            *(short4v*)&w0h[cc][ch] = s;
        }
        {
            const float4v v = *(const float4v*)(Wi1 + off);
            short4v s; s[0] = f2bf(v[0]); s[1] = f2bf(v[1]); s[2] = f2bf(v[2]); s[3] = f2bf(v[3]);
            *(short4v*)&w1x[cc][ch] = s;
        }
        {
            const float4v v = *(const float4v*)(Wh1 + off);
            short4v s; s[0] = f2bf(v[0]); s[1] = f2bf(v[1]); s[2] = f2bf(v[2]); s[3] = f2bf(v[3]);
            *(short4v*)&w1h[cc][ch] = s;
        }
    }
    if (tid < 16) {
        bias0[tid] = bi0[GROW(tid)] + bh0[GROW(tid)];
        bias1[tid] = bi1[GROW(tid)] + bh1[GROW(tid)];
    }
    // ---- state init ----
    cl0[b][uu] = c0in[ci];
    cl1[b][uu] = c0in[BH + ci];
    h0b[BH + ci] = f2bf(h0in[ci]);
    h1b[BH + ci] = f2bf(h0in[BH + ci]);

    // ---- barrier state init (coherent stores, WG 0) ----
    if (wg == 0) {
        for (int i = tid; i < 320; i += 256)
            __hip_atomic_store(bar + i, 0u, __ATOMIC_RELAXED, __HIP_MEMORY_SCOPE_AGENT);
    }

    // ---- pre-convert x to bf16 in ws (grid-strided) ----
    if (use_pre) {
        const size_t gtid = (size_t)blockIdx.x * 256 + tid;
        for (size_t i = gtid * 4; i < NX; i += (size_t)65536 * 4) {
            const float4v v = *(const float4v*)(xf + i);
            short4v s; s[0] = f2bf(v[0]); s[1] = f2bf(v[1]); s[2] = f2bf(v[2]); s[3] = f2bf(v[3]);
            *(short4v*)(xbf + i) = s;
        }
    }

    // Bootstrap sync (CG, once): h/x/barrier init visible everywhere.
    cg::grid_group grid = cg::this_grid();
    __threadfence();
    grid.sync();

    const float4v z = {0.f, 0.f, 0.f, 0.f};

    // Super-step s: layer 0 computes t=s, layer 1 computes t=s-1.
    for (int s = 0; s <= T_STEPS; ++s) {
        if (s > 0) {
            __syncthreads();
            if (tid == 0) grid_bar(bar, wg, (unsigned)s);
            __syncthreads();
        }

        if (s < T_STEPS) {  // ---- layer 0, t = s ----
            float4v acc[4] = {z, z, z, z};
            if (use_pre)
                gemm_seg<4>(xbf + (size_t)s * BATCH * IN_DIM, IN_DIM,
                            &w0x[0][0], 520, wave * 128, col, kq, acc);
            else
                gemm_seg_f32<4>(xf + (size_t)s * BATCH * IN_DIM, IN_DIM,
                                &w0x[0][0], 520, wave * 128, col, kq, acc);
            gemm_seg<8>(h0b + (size_t)((s + 1) & 1) * BH, HID,
                        &w0h[0][0], 1032, wave * 256, col, kq, acc);
#pragma unroll
            for (int mt = 0; mt < 4; ++mt)
#pragma unroll
                for (int r = 0; r < 4; ++r)
                    gbuf[wave][mt * 16 + kq * 4 + r][col] = acc[mt][r];
            __syncthreads();
            {
                const float gi = gbuf[0][b][uu]      + gbuf[1][b][uu]      + gbuf[2][b][uu]      + gbuf[3][b][uu]      + bias0[uu];
                const float gf = gbuf[0][b][4 + uu]  + gbuf[1][b][4 + uu]  + gbuf[2][b][4 + uu]  + gbuf[3][b][4 + uu]  + bias0[4 + uu];
                const float gg = gbuf[0][b][8 + uu]  + gbuf[1][b][8 + uu]  + gbuf[2][b][8 + uu]  + gbuf[3][b][8 + uu]  + bias0[8 + uu];
                const float go = gbuf[0][b][12 + uu] + gbuf[1][b][12 + uu] + gbuf[2][b][12 + uu] + gbuf[3][b][12 + uu] + bias0[12 + uu];
                const float cn = sigmoidf_(gf) * cl0[b][uu] + sigmoidf_(gi) * tanhf(gg);
                const float hn = sigmoidf_(go) * tanhf(cn);
                cl0[b][uu] = cn;
                h0b[(size_t)(s & 1) * BH + ci] = f2bf(hn);
            }
            __syncthreads();  // gbuf reused by layer 1
        }

        if (s >= 1) {  // ---- layer 1, t = s-1 ----
            const int t = s - 1;
            float4v acc[4] = {z, z, z, z};
            gemm_seg<8>(h0b + (size_t)(t & 1) * BH, HID,
                        &w1x[0][0], 1032, wave * 256, col, kq, acc);
            gemm_seg<8>(h1b + (size_t)(s & 1) * BH, HID,
                        &w1h[0][0], 1032, wave * 256, col, kq, acc);
#pragma unroll
            for (int mt = 0; mt < 4; ++mt)
#pragma unroll
                for (int r = 0; r < 4; ++r)
                    gbuf[wave][mt * 16 + kq * 4 + r][col] = acc[mt][r];
            __syncthreads();
            {
                const float gi = gbuf[0][b][uu]      + gbuf[1][b][uu]      + gbuf[2][b][uu]      + gbuf[3][b][uu]      + bias1[uu];
                const float gf = gbuf[0][b][4 + uu]  + gbuf[1][b][4 + uu]  + gbuf[2][b][4 + uu]  + gbuf[3][b][4 + uu]  + bias1[4 + uu];
                const float gg = gbuf[0][b][8 + uu]  + gbuf[1][b][8 + uu]  + gbuf[2][b][8 + uu]  + gbuf[3][b][8 + uu]  + bias1[8 + uu];
                const float go = gbuf[0][b][12 + uu] + gbuf[1][b][12 + uu] + gbuf[2][b][12 + uu] + gbuf[3][b][12 + uu] + bias1[12 + uu];
                const float cn = sigmoidf_(gf) * cl1[b][uu] + sigmoidf_(gi) * tanhf(gg);
                const float hn = sigmoidf_(go) * tanhf(cn);
                cl1[b][uu] = cn;
                h1b[(size_t)(t & 1) * BH + ci] = f2bf(hn);
                out[(size_t)t * BH + ci] = hn;    // ops[t] (fp32)
            }
            __syncthreads();
        }
    }

    // ---- final hT, cT (own-thread data) ----
    out[OPS_SZ + ci]                   = bf2f(h0b[(size_t)((T_STEPS - 1) & 1) * BH + ci]);
    out[OPS_SZ + BH + ci]              = bf2f(h1b[(size_t)((T_STEPS - 1) & 1) * BH + ci]);
    out[OPS_SZ + 2 * (size_t)BH + ci]  = cl0[b][uu];
    out[OPS_SZ + 3 * (size_t)BH + ci]  = cl1[b][uu];
#undef GROW
}

extern "C" void kernel_launch(void* const* d_in, const int* in_sizes, int n_in,
                              void* d_out, int out_size, void* d_ws, size_t ws_size,
                              hipStream_t stream)
{
    const float* x    = (const float*)d_in[0];
    const float* h0   = (const float*)d_in[1];
    const float* c0   = (const float*)d_in[2];
    const float* Wi0  = (const float*)d_in[3];
    const float* Wh0  = (const float*)d_in[4];
    const float* bi0  = (const float*)d_in[5];
    const float* bh0  = (const float*)d_in[6];
    const float* Wi1  = (const float*)d_in[7];
    const float* Wh1  = (const float*)d_in[8];
    const float* bi1  = (const float*)d_in[9];
    const float* bh1  = (const float*)d_in[10];
    float* out = (float*)d_out;

    // ws: [barrier 2048 B][2*BH short h0][2*BH short h1][NX short xbf]
    unsigned* bar = (unsigned*)d_ws;
    short* h0b = (short*)((char*)d_ws + BAR_BYTES);
    short* h1b = h0b + (size_t)2 * BH;
    short* xbf = h1b + (size_t)2 * BH;
    int use_pre = (ws_size >= BAR_BYTES + ((size_t)4 * BH + NX) * sizeof(short)) ? 1 : 0;

    void* args[] = {(void*)&x, (void*)&Wi0, (void*)&Wh0, (void*)&bi0, (void*)&bh0,
                    (void*)&Wi1, (void*)&Wh1, (void*)&bi1, (void*)&bh1,
                    (void*)&h0, (void*)&c0, (void*)&out,
                    (void*)&bar, (void*)&h0b, (void*)&h1b, (void*)&xbf, (void*)&use_pre};
    hipLaunchCooperativeKernel((void*)lstm_persistent, dim3(NWG), dim3(256),
                               args, 0, stream);
}

// Round 5
// 10925.179 us; speedup vs baseline: 3.1666x; 1.0924x over previous
//
#include <hip/hip_runtime.h>
#include <hip/hip_cooperative_groups.h>
#include <cstdint>
#include <cstddef>

namespace cg = cooperative_groups;

typedef __attribute__((ext_vector_type(8))) short short8;
typedef __attribute__((ext_vector_type(4))) short short4v;
typedef __attribute__((ext_vector_type(4))) float float4v;

#define T_STEPS 512
#define BATCH   64
#define IN_DIM  512
#define HID     1024
#define BH      (BATCH * HID)              /* 65536 */
#define OPS_SZ  ((size_t)T_STEPS * BH)     /* 33554432 */
#define NX      ((size_t)T_STEPS * BATCH * IN_DIM) /* 16777216 */
#define NWG     256
#define BAR_BYTES 2048

__device__ __forceinline__ float bf2f(unsigned short b) {
    return __builtin_bit_cast(float, ((unsigned)b) << 16);
}
__device__ __forceinline__ short f2bf(float f) {
    unsigned u = __builtin_bit_cast(unsigned, f);
    unsigned r = (u + 0x7FFFu + ((u >> 16) & 1u)) >> 16;   // round-nearest-even
    return (short)(unsigned short)r;
}
__device__ __forceinline__ float sigmoidf_(float v) { return 1.0f / (1.0f + __expf(-v)); }

struct u64x2 { unsigned long long a, b; };

// Coherent (agent-scope, L1/L2-bypassing) 16 B load of a bf16x8 fragment.
// Compiler-scheduled -> retains MLP across the unrolled K loop.
__device__ __forceinline__ short8 cohload8(const short* p) {
    unsigned long long* q = (unsigned long long*)p;
    u64x2 t;
    t.a = __hip_atomic_load(q,     __ATOMIC_RELAXED, __HIP_MEMORY_SCOPE_AGENT);
    t.b = __hip_atomic_load(q + 1, __ATOMIC_RELAXED, __HIP_MEMORY_SCOPE_AGENT);
    return __builtin_bit_cast(short8, t);
}
__device__ __forceinline__ void cohstore_h(short* p, short v) {
    __hip_atomic_store((unsigned short*)p, (unsigned short)v,
                       __ATOMIC_RELAXED, __HIP_MEMORY_SCOPE_AGENT);
}
__device__ __forceinline__ unsigned short cohload_h(const short* p) {
    return __hip_atomic_load((unsigned short*)p, __ATOMIC_RELAXED, __HIP_MEMORY_SCOPE_AGENT);
}

// Pure-atomic grid barrier: NO L2 writeback / invalidate. All cross-WG data
// (h state) moves via agent-scope coherent ops, so only ordering is needed.
__device__ __forceinline__ void grid_bar(unsigned* bar, int wg, unsigned e)
{
    asm volatile("s_waitcnt vmcnt(0)" ::: "memory");  // h write-through stores acked
    unsigned* sub  = bar + (wg >> 5) * 32;            // 8 counters, 128 B apart
    unsigned* root = bar + 256;
    unsigned* go   = bar + 288;
    __atomic_signal_fence(__ATOMIC_SEQ_CST);
    if (__hip_atomic_fetch_add(sub, 1u, __ATOMIC_RELAXED, __HIP_MEMORY_SCOPE_AGENT) == e * 32u - 1u)
        if (__hip_atomic_fetch_add(root, 1u, __ATOMIC_RELAXED, __HIP_MEMORY_SCOPE_AGENT) == e * 8u - 1u)
            __hip_atomic_store(go, e, __ATOMIC_RELAXED, __HIP_MEMORY_SCOPE_AGENT);
    while (__hip_atomic_load(go, __ATOMIC_RELAXED, __HIP_MEMORY_SCOPE_AGENT) < e)
        __builtin_amdgcn_s_sleep(1);
    __atomic_signal_fence(__ATOMIC_SEQ_CST);          // no hoisting of h loads above spin
}

// Plain-load GEMM (read-only A: x).  C[64x16] += A[64xKseg] * W[16xKseg]^T.
template <int NC>
__device__ __forceinline__ void gemm_seg(const short* __restrict__ A, int lda,
                                         const short* __restrict__ W, int ldw,
                                         int kbase, int col, int kq, float4v* acc)
{
#pragma unroll
    for (int kc = 0; kc < NC; ++kc) {
        const int k = kbase + kc * 32 + kq * 8;
        const short8 b = *(const short8*)(W + col * ldw + k);
#pragma unroll
        for (int mt = 0; mt < 4; ++mt) {
            const short8 a = *(const short8*)(A + (size_t)(mt * 16 + col) * lda + k);
            acc[mt] = __builtin_amdgcn_mfma_f32_16x16x32_bf16(a, b, acc[mt], 0, 0, 0);
        }
    }
}

// fp32-A fallback (x not pre-converted).
template <int NC>
__device__ __forceinline__ void gemm_seg_f32(const float* __restrict__ A, int lda,
                                             const short* __restrict__ W, int ldw,
                                             int kbase, int col, int kq, float4v* acc)
{
#pragma unroll
    for (int kc = 0; kc < NC; ++kc) {
        const int k = kbase + kc * 32 + kq * 8;
        const short8 b = *(const short8*)(W + col * ldw + k);
#pragma unroll
        for (int mt = 0; mt < 4; ++mt) {
            const float* ap = A + (size_t)(mt * 16 + col) * lda + k;
            const float4v a0 = *(const float4v*)ap;
            const float4v a1 = *(const float4v*)(ap + 4);
            short8 a;
            a[0] = f2bf(a0[0]); a[1] = f2bf(a0[1]); a[2] = f2bf(a0[2]); a[3] = f2bf(a0[3]);
            a[4] = f2bf(a1[0]); a[5] = f2bf(a1[1]); a[6] = f2bf(a1[2]); a[7] = f2bf(a1[3]);
            acc[mt] = __builtin_amdgcn_mfma_f32_16x16x32_bf16(a, b, acc[mt], 0, 0, 0);
        }
    }
}

// Coherent-A GEMM, single W.
template <int NC>
__device__ __forceinline__ void gemm_coh1(const short* A, int lda,
                                          const short* __restrict__ W, int ldw,
                                          int kbase, int col, int kq, float4v* acc)
{
#pragma unroll
    for (int kc = 0; kc < NC; ++kc) {
        const int k = kbase + kc * 32 + kq * 8;
        const short8 b = *(const short8*)(W + col * ldw + k);
#pragma unroll
        for (int mt = 0; mt < 4; ++mt) {
            const short8 a = cohload8(A + (size_t)(mt * 16 + col) * lda + k);
            acc[mt] = __builtin_amdgcn_mfma_f32_16x16x32_bf16(a, b, acc[mt], 0, 0, 0);
        }
    }
}

// Coherent-A GEMM, FUSED two W (one A read feeds both accumulators).
template <int NC>
__device__ __forceinline__ void gemm_coh2(const short* A, int lda,
                                          const short* __restrict__ W0,
                                          const short* __restrict__ W1, int ldw,
                                          int kbase, int col, int kq,
                                          float4v* acc0, float4v* acc1)
{
#pragma unroll
    for (int kc = 0; kc < NC; ++kc) {
        const int k = kbase + kc * 32 + kq * 8;
        const short8 b0 = *(const short8*)(W0 + col * ldw + k);
        const short8 b1 = *(const short8*)(W1 + col * ldw + k);
#pragma unroll
        for (int mt = 0; mt < 4; ++mt) {
            const short8 a = cohload8(A + (size_t)(mt * 16 + col) * lda + k);
            acc0[mt] = __builtin_amdgcn_mfma_f32_16x16x32_bf16(a, b0, acc0[mt], 0, 0, 0);
            acc1[mt] = __builtin_amdgcn_mfma_f32_16x16x32_bf16(a, b1, acc1[mt], 0, 0, 0);
        }
    }
}

__global__ void __launch_bounds__(256, 1)
lstm_persistent(const float* __restrict__ xf,
                const float* __restrict__ Wi0, const float* __restrict__ Wh0,
                const float* __restrict__ bi0, const float* __restrict__ bh0,
                const float* __restrict__ Wi1, const float* __restrict__ Wh1,
                const float* __restrict__ bi1, const float* __restrict__ bh1,
                const float* __restrict__ h0in, const float* __restrict__ c0in,
                float* __restrict__ out,
                unsigned* __restrict__ bar,
                short* __restrict__ h0b,   // ws: [2][BH] bf16 L0 h dbuf (coherent)
                short* __restrict__ h1b,   // ws: [2][BH] bf16 L1 h dbuf (coherent)
                short* __restrict__ xbf,   // ws: [NX] bf16 x
                int use_pre)
{
    __shared__ short w0x[16][520];
    __shared__ short w0h[16][1032];
    __shared__ short w1x[16][1032];
    __shared__ short w1h[16][1032];
    __shared__ float gbuf[4][64][17];
    __shared__ float bias0[16], bias1[16];
    __shared__ float cl0[64][4], cl1[64][4];

    const int wg   = blockIdx.x;
    const int tid  = threadIdx.x;
    const int wave = tid >> 6;
    const int lane = tid & 63;
    const int col  = lane & 15;
    const int kq   = lane >> 4;
    const int u0   = wg << 2;
    const int b    = tid >> 2;
    const int uu   = tid & 3;
    const int ug   = u0 + uu;
    const size_t ci = (size_t)b * HID + ug;

#define GROW(cc) ((size_t)((cc) >> 2) * HID + u0 + ((cc) & 3))
    for (int idx = tid; idx < 16 * 128; idx += 256) {
        const int cc = idx >> 7, ch = (idx & 127) << 2;
        const float4v v = *(const float4v*)(Wi0 + GROW(cc) * IN_DIM + ch);
        short4v s; s[0] = f2bf(v[0]); s[1] = f2bf(v[1]); s[2] = f2bf(v[2]); s[3] = f2bf(v[3]);
        *(short4v*)&w0x[cc][ch] = s;
    }
    for (int idx = tid; idx < 16 * 256; idx += 256) {
        const int cc = idx >> 8, ch = (idx & 255) << 2;
        const size_t off = GROW(cc) * HID + ch;
        {
            const float4v v = *(const float4v*)(Wh0 + off);
            short4v s; s[0] = f2bf(v[0]); s[1] = f2bf(v[1]); s[2] = f2bf(v[2]); s[3] = f2bf(v[3]);
            *(short4v*)&w0h[cc][ch] = s;
        }
        {
            const float4v v = *(const float4v*)(Wi1 + off);
            short4v s; s[0] = f2bf(v[0]); s[1] = f2bf(v[1]); s[2] = f2bf(v[2]); s[3] = f2bf(v[3]);
            *(short4v*)&w1x[cc][ch] = s;
        }
        {
            const float4v v = *(const float4v*)(Wh1 + off);
            short4v s; s[0] = f2bf(v[0]); s[1] = f2bf(v[1]); s[2] = f2bf(v[2]); s[3] = f2bf(v[3]);
            *(short4v*)&w1h[cc][ch] = s;
        }
    }
    if (tid < 16) {
        bias0[tid] = bi0[GROW(tid)] + bh0[GROW(tid)];
        bias1[tid] = bi1[GROW(tid)] + bh1[GROW(tid)];
    }
    cl0[b][uu] = c0in[ci];
    cl1[b][uu] = c0in[BH + ci];
    h0b[BH + ci] = f2bf(h0in[ci]);          // plain; CG sync below publishes
    h1b[BH + ci] = f2bf(h0in[BH + ci]);

    if (wg == 0) {
        for (int i = tid; i < 320; i += 256)
            __hip_atomic_store(bar + i, 0u, __ATOMIC_RELAXED, __HIP_MEMORY_SCOPE_AGENT);
    }
    if (use_pre) {
        const size_t gtid = (size_t)blockIdx.x * 256 + tid;
        for (size_t i = gtid * 4; i < NX; i += (size_t)65536 * 4) {
            const float4v v = *(const float4v*)(xf + i);
            short4v s; s[0] = f2bf(v[0]); s[1] = f2bf(v[1]); s[2] = f2bf(v[2]); s[3] = f2bf(v[3]);
            *(short4v*)(xbf + i) = s;
        }
    }

    cg::grid_group grid = cg::this_grid();   // bootstrap: full release-acquire once
    __threadfence();
    grid.sync();

    const float4v z = {0.f, 0.f, 0.f, 0.f};

    // Super-step s: layer 0 computes t=s, layer 1 computes t=s-1.
    for (int s = 0; s <= T_STEPS; ++s) {
        if (s > 0) {
            __syncthreads();
            if (tid == 0) grid_bar(bar, wg, (unsigned)s);
            __syncthreads();
        }
        const short* h0p = h0b + (size_t)((s + 1) & 1) * BH;  // h0(s-1), also L1's input
        const short* h1p = h1b + (size_t)(s & 1) * BH;        // h1(s-2)

        float4v accL0[4] = {z, z, z, z};
        float4v accL1[4] = {z, z, z, z};

        if (s < T_STEPS) {
            if (use_pre)
                gemm_seg<4>(xbf + (size_t)s * BATCH * IN_DIM, IN_DIM,
                            &w0x[0][0], 520, wave * 128, col, kq, accL0);
            else
                gemm_seg_f32<4>(xf + (size_t)s * BATCH * IN_DIM, IN_DIM,
                                &w0x[0][0], 520, wave * 128, col, kq, accL0);
            // fused: one coherent read of h0_prev feeds Wh0 (layer0) and Wi1 (layer1)
            gemm_coh2<8>(h0p, HID, &w0h[0][0], &w1x[0][0], 1032,
                         wave * 256, col, kq, accL0, accL1);
        } else {
            gemm_coh1<8>(h0p, HID, &w1x[0][0], 1032, wave * 256, col, kq, accL1);
        }
        if (s >= 1)
            gemm_coh1<8>(h1p, HID, &w1h[0][0], 1032, wave * 256, col, kq, accL1);

        if (s < T_STEPS) {  // ---- layer 0 reduce + elementwise ----
#pragma unroll
            for (int mt = 0; mt < 4; ++mt)
#pragma unroll
                for (int r = 0; r < 4; ++r)
                    gbuf[wave][mt * 16 + kq * 4 + r][col] = accL0[mt][r];
            __syncthreads();
            {
                const float gi = gbuf[0][b][uu]      + gbuf[1][b][uu]      + gbuf[2][b][uu]      + gbuf[3][b][uu]      + bias0[uu];
                const float gf = gbuf[0][b][4 + uu]  + gbuf[1][b][4 + uu]  + gbuf[2][b][4 + uu]  + gbuf[3][b][4 + uu]  + bias0[4 + uu];
                const float gg = gbuf[0][b][8 + uu]  + gbuf[1][b][8 + uu]  + gbuf[2][b][8 + uu]  + gbuf[3][b][8 + uu]  + bias0[8 + uu];
                const float go = gbuf[0][b][12 + uu] + gbuf[1][b][12 + uu] + gbuf[2][b][12 + uu] + gbuf[3][b][12 + uu] + bias0[12 + uu];
                const float cn = sigmoidf_(gf) * cl0[b][uu] + sigmoidf_(gi) * tanhf(gg);
                const float hn = sigmoidf_(go) * tanhf(cn);
                cl0[b][uu] = cn;
                cohstore_h(h0b + (size_t)(s & 1) * BH + ci, f2bf(hn));
            }
            __syncthreads();  // gbuf reuse by layer 1
        }

        if (s >= 1) {  // ---- layer 1 reduce + elementwise (t = s-1) ----
            const int t = s - 1;
#pragma unroll
            for (int mt = 0; mt < 4; ++mt)
#pragma unroll
                for (int r = 0; r < 4; ++r)
                    gbuf[wave][mt * 16 + kq * 4 + r][col] = accL1[mt][r];
            __syncthreads();
            {
                const float gi = gbuf[0][b][uu]      + gbuf[1][b][uu]      + gbuf[2][b][uu]      + gbuf[3][b][uu]      + bias1[uu];
                const float gf = gbuf[0][b][4 + uu]  + gbuf[1][b][4 + uu]  + gbuf[2][b][4 + uu]  + gbuf[3][b][4 + uu]  + bias1[4 + uu];
                const float gg = gbuf[0][b][8 + uu]  + gbuf[1][b][8 + uu]  + gbuf[2][b][8 + uu]  + gbuf[3][b][8 + uu]  + bias1[8 + uu];
                const float go = gbuf[0][b][12 + uu] + gbuf[1][b][12 + uu] + gbuf[2][b][12 + uu] + gbuf[3][b][12 + uu] + bias1[12 + uu];
                const float cn = sigmoidf_(gf) * cl1[b][uu] + sigmoidf_(gi) * tanhf(gg);
                const float hn = sigmoidf_(go) * tanhf(cn);
                cl1[b][uu] = cn;
                cohstore_h(h1b + (size_t)(t & 1) * BH + ci, f2bf(hn));
                out[(size_t)t * BH + ci] = hn;   // plain store, write-only stream
            }
            __syncthreads();
        }
    }

    out[OPS_SZ + ci]                  = bf2f(cohload_h(h0b + (size_t)((T_STEPS - 1) & 1) * BH + ci));
    out[OPS_SZ + BH + ci]             = bf2f(cohload_h(h1b + (size_t)((T_STEPS - 1) & 1) * BH + ci));
    out[OPS_SZ + 2 * (size_t)BH + ci] = cl0[b][uu];
    out[OPS_SZ + 3 * (size_t)BH + ci] = cl1[b][uu];
#undef GROW
}

extern "C" void kernel_launch(void* const* d_in, const int* in_sizes, int n_in,
                              void* d_out, int out_size, void* d_ws, size_t ws_size,
                              hipStream_t stream)
{
    const float* x    = (const float*)d_in[0];
    const float* h0   = (const float*)d_in[1];
    const float* c0   = (const float*)d_in[2];
    const float* Wi0  = (const float*)d_in[3];
    const float* Wh0  = (const float*)d_in[4];
    const float* bi0  = (const float*)d_in[5];
    const float* bh0  = (const float*)d_in[6];
    const float* Wi1  = (const float*)d_in[7];
    const float* Wh1  = (const float*)d_in[8];
    const float* bi1  = (const float*)d_in[9];
    const float* bh1  = (const float*)d_in[10];
    float* out = (float*)d_out;

    unsigned* bar = (unsigned*)d_ws;
    short* h0b = (short*)((char*)d_ws + BAR_BYTES);
    short* h1b = h0b + (size_t)2 * BH;
    short* xbf = h1b + (size_t)2 * BH;
    int use_pre = (ws_size >= BAR_BYTES + ((size_t)4 * BH + NX) * sizeof(short)) ? 1 : 0;

    void* args[] = {(void*)&x, (void*)&Wi0, (void*)&Wh0, (void*)&bi0, (void*)&bh0,
                    (void*)&Wi1, (void*)&Wh1, (void*)&bi1, (void*)&bh1,
                    (void*)&h0, (void*)&c0, (void*)&out,
                    (void*)&bar, (void*)&h0b, (void*)&h1b, (void*)&xbf, (void*)&use_pre};
    hipLaunchCooperativeKernel((void*)lstm_persistent, dim3(NWG), dim3(256),
                               args, 0, stream);
}